// Round 2
// baseline (798.425 us; speedup 1.0000x reference)
//
#include <hip/hip_runtime.h>
#include <hip/hip_bf16.h>

#define MN 16384
#define SPLITS 4
#define KSLICE (MN / SPLITS)     // 4096
#define BK 64
#define NSTEPS (KSLICE / BK)     // 64

typedef float f32x4 __attribute__((ext_vector_type(4)));
typedef short s16x8 __attribute__((ext_vector_type(8)));
typedef unsigned short u16x8 __attribute__((ext_vector_type(8)));
typedef unsigned short u16;

__device__ __forceinline__ u16 f2bf(float f) {
  unsigned u = __builtin_bit_cast(unsigned, f);
  u += 0x7FFFu + ((u >> 16) & 1u);   // round-to-nearest-even
  return (u16)(u >> 16);
}

// ---------------------------------------------------------------------------
// K1: support1 = x @ W2, written as bf16 in MFMA-fragment order:
//     B1[( (k>>3)*128 + col )*8 + (k&7)]  (k = row index of support1)
// ---------------------------------------------------------------------------
__global__ __launch_bounds__(256)
void k1_xw2(const float* __restrict__ x, const float* __restrict__ W2,
            u16* __restrict__ B1) {
  __shared__ __align__(16) float xs[64 * 128];
  const int t = threadIdx.x;
  const long rowbase = (long)blockIdx.x * 64;
  const f32x4* xg = (const f32x4*)(x + rowbase * 128);
  f32x4* xl = (f32x4*)xs;
#pragma unroll
  for (int i = 0; i < 8; ++i) xl[t + 256 * i] = xg[t + 256 * i];
  __syncthreads();
  const int r0 = (t >> 5) * 8;   // 8 rows per thread (8-aligned)
  const int c0 = (t & 31) * 4;   // 4 cols per thread
  float acc[8][4] = {};
  for (int k = 0; k < 128; k += 4) {
    f32x4 w[4];
#pragma unroll
    for (int kk = 0; kk < 4; ++kk) w[kk] = *(const f32x4*)(W2 + (k + kk) * 128 + c0);
#pragma unroll
    for (int i = 0; i < 8; ++i) {
      f32x4 xv = *(const f32x4*)(xs + (r0 + i) * 128 + k);
#pragma unroll
      for (int kk = 0; kk < 4; ++kk)
#pragma unroll
        for (int j = 0; j < 4; ++j) acc[i][j] += xv[kk] * w[kk][j];
    }
  }
  const long R8 = (rowbase + r0) >> 3;
#pragma unroll
  for (int j = 0; j < 4; ++j) {
    u16x8 v;
#pragma unroll
    for (int i = 0; i < 8; ++i) v[i] = f2bf(acc[i][j]);
    *(u16x8*)(B1 + (R8 * 128 + (c0 + j)) * 8) = v;
  }
}

// ---------------------------------------------------------------------------
// Big kernel v2: P[s] = adj[:, k-slice s] @ B  (B in bf16 fragment order).
// NO LDS, NO barriers: B fragments are loaded directly from global (B slice
// is 1 MB -> L1/L2-resident; XCD-swizzled block mapping pins one slice per
// XCD's L2). Waves fully independent -> pure TLP hides HBM latency on the
// nontemporal A stream. 256 threads = 4 waves, each wave owns 16 rows of a
// 64-row tile; full N=128 via 8 col-tiles of mfma_f32_16x16x32_bf16.
// ---------------------------------------------------------------------------
__global__ __launch_bounds__(256)
void big_mm(const float* __restrict__ A, const u16* __restrict__ Bswz,
            float* __restrict__ P) {
  const int tid  = threadIdx.x;
  const int wid  = tid >> 6;
  const int lane = tid & 63;
  const int g    = lane >> 4;    // k-group (lane reads only its own g-quarter of B)
  const int cl   = lane & 15;    // A-row / B-col / C-col within tile
  // XCD-aware mapping: default assignment XCD = blockIdx.x % 8; give each XCD
  // a single k-slice s (2 XCDs per slice) so its L2 holds one 1 MB B-slice.
  const int u = blockIdx.x & 7;
  const int v = blockIdx.x >> 3;           // 0..127
  const int s = u >> 1;                    // k-slice
  const int tile_m = (u & 1) * 128 + v;    // 0..255 (64-row tiles)
  const long k0 = (long)s * KSLICE;

  const float* aptr = A + (long)(tile_m * 64 + wid * 16 + cl) * MN + k0 + 8 * g;
  const u16x8* bptr = (const u16x8*)Bswz + (k0 >> 3) * 128 + g * 128 + cl;

  f32x4 acc[8] = {};

  for (int t = 0; t < NSTEPS; ++t) {
    const float* ap = aptr + (long)t * BK;
    f32x4 a0 = __builtin_nontemporal_load((const f32x4*)ap);
    f32x4 a1 = __builtin_nontemporal_load((const f32x4*)(ap + 4));
    f32x4 a2 = __builtin_nontemporal_load((const f32x4*)(ap + 32));
    f32x4 a3 = __builtin_nontemporal_load((const f32x4*)(ap + 36));
    const u16x8* bb = bptr + (long)t * 1024;   // 8 k-units of 128 cols per step
    s16x8 af0, af1;
#pragma unroll
    for (int j = 0; j < 4; ++j) {
      af0[j]     = (short)f2bf(a0[j]);
      af0[4 + j] = (short)f2bf(a1[j]);
      af1[j]     = (short)f2bf(a2[j]);
      af1[4 + j] = (short)f2bf(a3[j]);
    }
#pragma unroll
    for (int c = 0; c < 8; ++c) {
      u16x8 b0 = bb[16 * c];          // k = 8g..8g+7   of this step
      u16x8 b1 = bb[512 + 16 * c];    // k = 32+8g..32+8g+7
      acc[c] = __builtin_amdgcn_mfma_f32_16x16x32_bf16(
          af0, __builtin_bit_cast(s16x8, b0), acc[c], 0, 0, 0);
      acc[c] = __builtin_amdgcn_mfma_f32_16x16x32_bf16(
          af1, __builtin_bit_cast(s16x8, b1), acc[c], 0, 0, 0);
    }
  }

  // C/D layout (HW-verified): col = lane&15, row = 4*(lane>>4) + reg
  float* pb = P + ((long)s * MN + tile_m * 64 + wid * 16) * 128;
#pragma unroll
  for (int c = 0; c < 8; ++c)
#pragma unroll
    for (int q = 0; q < 4; ++q)
      __builtin_nontemporal_store(acc[c][q], &pb[(g * 4 + q) * 128 + 16 * c + cl]);
}

// ---------------------------------------------------------------------------
// K3: LH = sum_s P[s] + b2 (tile in LDS); then
//     B2 = bf16frag(LH @ W4);  R = LH @ res_w^T + res_b + b4
// ---------------------------------------------------------------------------
__global__ __launch_bounds__(256)
void k3_mid(const float* __restrict__ P, const float* __restrict__ b2,
            const float* __restrict__ W4, const float* __restrict__ res_w,
            const float* __restrict__ b4, const float* __restrict__ res_b,
            u16* __restrict__ B2, float* __restrict__ Rr) {
  __shared__ __align__(16) float hs[64 * 128];
  const int t = threadIdx.x;
  const long rowbase = (long)blockIdx.x * 64;
  const long base = rowbase * 32;            // f32x4 units (128/4 per row)
  const f32x4* P0 = (const f32x4*)P + base;
  const f32x4* P1 = (const f32x4*)P + (long)MN * 32 + base;
  const f32x4* P2 = (const f32x4*)P + 2L * MN * 32 + base;
  const f32x4* P3 = (const f32x4*)P + 3L * MN * 32 + base;
  const f32x4* b2v = (const f32x4*)b2;
  f32x4* hl = (f32x4*)hs;
#pragma unroll
  for (int i = 0; i < 8; ++i) {
    int idx = t + 256 * i;
    f32x4 v = __builtin_nontemporal_load(P0 + idx);
    v += __builtin_nontemporal_load(P1 + idx);
    v += __builtin_nontemporal_load(P2 + idx);
    v += __builtin_nontemporal_load(P3 + idx);
    hl[idx] = v + b2v[idx & 31];
  }
  __syncthreads();
  const int r0 = (t >> 5) * 8;
  const int c0 = (t & 31) * 4;
  float acc2[8][4] = {};
  float accR[8][4] = {};
  for (int k = 0; k < 128; k += 4) {
    f32x4 w4v[4], rwv[4];
#pragma unroll
    for (int kk = 0; kk < 4; ++kk) w4v[kk] = *(const f32x4*)(W4 + (k + kk) * 128 + c0);
#pragma unroll
    for (int j = 0; j < 4; ++j) rwv[j] = *(const f32x4*)(res_w + (c0 + j) * 128 + k);
#pragma unroll
    for (int i = 0; i < 8; ++i) {
      f32x4 xv = *(const f32x4*)(hs + (r0 + i) * 128 + k);
#pragma unroll
      for (int kk = 0; kk < 4; ++kk)
#pragma unroll
        for (int j = 0; j < 4; ++j) {
          acc2[i][j] += xv[kk] * w4v[kk][j];
          accR[i][j] += xv[kk] * rwv[j][kk];
        }
    }
  }
  const long R8 = (rowbase + r0) >> 3;
#pragma unroll
  for (int j = 0; j < 4; ++j) {
    u16x8 v;
#pragma unroll
    for (int i = 0; i < 8; ++i) v[i] = f2bf(acc2[i][j]);
    *(u16x8*)(B2 + (R8 * 128 + (c0 + j)) * 8) = v;
  }
  const f32x4 b4v = *(const f32x4*)(b4 + c0);
  const f32x4 rbv = *(const f32x4*)(res_b + c0);
#pragma unroll
  for (int i = 0; i < 8; ++i) {
    f32x4 rv;
#pragma unroll
    for (int j = 0; j < 4; ++j) rv[j] = accR[i][j];
    rv += b4v + rbv;
    *(f32x4*)(Rr + (rowbase + r0 + i) * 128 + c0) = rv;
  }
}

// ---------------------------------------------------------------------------
// K5: out = sum_s P[s] + R
// ---------------------------------------------------------------------------
__global__ __launch_bounds__(256)
void k5_out(const float* __restrict__ P, const float* __restrict__ Rr,
            float* __restrict__ out) {
  const long i = (long)blockIdx.x * 256 + threadIdx.x;   // f32x4 index
  const f32x4* P0 = (const f32x4*)P;
  const f32x4* P1 = P0 + (long)MN * 32;
  const f32x4* P2 = P0 + 2L * MN * 32;
  const f32x4* P3 = P0 + 3L * MN * 32;
  f32x4 v = __builtin_nontemporal_load(P0 + i);
  v += __builtin_nontemporal_load(P1 + i);
  v += __builtin_nontemporal_load(P2 + i);
  v += __builtin_nontemporal_load(P3 + i);
  v += *((const f32x4*)Rr + i);
  __builtin_nontemporal_store(v, (f32x4*)out + i);
}

extern "C" void kernel_launch(void* const* d_in, const int* in_sizes, int n_in,
                              void* d_out, int out_size, void* d_ws, size_t ws_size,
                              hipStream_t stream) {
  const float* x     = (const float*)d_in[0];
  const float* adj   = (const float*)d_in[1];
  const float* W2    = (const float*)d_in[2];
  const float* b2    = (const float*)d_in[3];
  const float* W4    = (const float*)d_in[4];
  const float* b4    = (const float*)d_in[5];
  const float* res_w = (const float*)d_in[6];
  const float* res_b = (const float*)d_in[7];
  float* out = (float*)d_out;

  char* ws = (char*)d_ws;
  u16*   B1 = (u16*)ws;                     // 4 MB  bf16-frag support1
  u16*   B2 = (u16*)(ws + (4L << 20));      // 4 MB  bf16-frag support2
  float* Rr = (float*)(ws + (8L << 20));    // 8 MB  residual + biases
  float* P  = (float*)(ws + (16L << 20));   // 32 MB split-K partials (reused)

  k1_xw2<<<dim3(256), dim3(256), 0, stream>>>(x, W2, B1);
  big_mm<<<dim3(256 * SPLITS), dim3(256), 0, stream>>>(adj, B1, P);
  k3_mid<<<dim3(256), dim3(256), 0, stream>>>(P, b2, W4, res_w, b4, res_b, B2, Rr);
  big_mm<<<dim3(256 * SPLITS), dim3(256), 0, stream>>>(adj, B2, P);
  k5_out<<<dim3(2048), dim3(256), 0, stream>>>(P, Rr, out);
}

// Round 3
// 561.745 us; speedup vs baseline: 1.4213x; 1.4213x over previous
//
#include <hip/hip_runtime.h>
#include <hip/hip_bf16.h>

#define MN 16384
#define SPLITS 4
#define KSLICE (MN / SPLITS)     // 4096
#define BK 64
#define NSTEPS (KSLICE / BK)     // 64

typedef float f32x4 __attribute__((ext_vector_type(4)));
typedef short s16x8 __attribute__((ext_vector_type(8)));
typedef unsigned short u16x8 __attribute__((ext_vector_type(8)));
typedef unsigned short u16;

__device__ __forceinline__ u16 f2bf(float f) {
  unsigned u = __builtin_bit_cast(unsigned, f);
  u += 0x7FFFu + ((u >> 16) & 1u);   // round-to-nearest-even
  return (u16)(u >> 16);
}

__device__ __forceinline__ void async16(void* lds, const void* g) {
  __builtin_amdgcn_global_load_lds(
      (const __attribute__((address_space(1))) unsigned int*)g,
      (__attribute__((address_space(3))) unsigned int*)lds, 16, 0, 0);
}

// ---------------------------------------------------------------------------
// K1: support1 = x @ W2, written as bf16 in MFMA-fragment order:
//     B1[( (k>>3)*128 + col )*8 + (k&7)]  (k = row index of support1)
// ---------------------------------------------------------------------------
__global__ __launch_bounds__(256)
void k1_xw2(const float* __restrict__ x, const float* __restrict__ W2,
            u16* __restrict__ B1) {
  __shared__ __align__(16) float xs[64 * 128];
  const int t = threadIdx.x;
  const long rowbase = (long)blockIdx.x * 64;
  const f32x4* xg = (const f32x4*)(x + rowbase * 128);
  f32x4* xl = (f32x4*)xs;
#pragma unroll
  for (int i = 0; i < 8; ++i) xl[t + 256 * i] = xg[t + 256 * i];
  __syncthreads();
  const int r0 = (t >> 5) * 8;   // 8 rows per thread (8-aligned)
  const int c0 = (t & 31) * 4;   // 4 cols per thread
  float acc[8][4] = {};
  for (int k = 0; k < 128; k += 4) {
    f32x4 w[4];
#pragma unroll
    for (int kk = 0; kk < 4; ++kk) w[kk] = *(const f32x4*)(W2 + (k + kk) * 128 + c0);
#pragma unroll
    for (int i = 0; i < 8; ++i) {
      f32x4 xv = *(const f32x4*)(xs + (r0 + i) * 128 + k);
#pragma unroll
      for (int kk = 0; kk < 4; ++kk)
#pragma unroll
        for (int j = 0; j < 4; ++j) acc[i][j] += xv[kk] * w[kk][j];
    }
  }
  const long R8 = (rowbase + r0) >> 3;
#pragma unroll
  for (int j = 0; j < 4; ++j) {
    u16x8 v;
#pragma unroll
    for (int i = 0; i < 8; ++i) v[i] = f2bf(acc[i][j]);
    *(u16x8*)(B1 + (R8 * 128 + (c0 + j)) * 8) = v;
  }
}

// ---------------------------------------------------------------------------
// Big kernel v3: P[s] = adj[:, k-slice s] @ B  (B in bf16 fragment order).
// 512 threads = 8 waves; 128-row tile; split-K = 4.
// B staged via global_load_lds into a 4-deep ring, prefetched 3 steps ahead.
// NO manual waitcnt in the loop; raw s_barrier per step (no vmcnt(0) drain).
// Correctness: in-order vmcnt retirement means the compiler's own wait for
// A(t) (issued after stage(t+2)) retires every wave's stages through t+2 —
// all issued >=1 step (~6400 cyc) earlier, so the wait is free. Cross-wave:
// W's stage(t+3) retires under W's A(t+1)-wait, >=2 barriers before any
// ds_read of buffer t+3. stage(t+3) overwrites buf (t-1)&3, whose readers
// all passed the end-of-(t-1) barrier.
// ---------------------------------------------------------------------------
__global__ __launch_bounds__(512, 4)
void big_mm(const float* __restrict__ A, const u16* __restrict__ Bswz,
            float* __restrict__ P) {
  __shared__ __align__(16) u16 Bs[4][8192];   // 4 x 16 KB (BK=64 x 128 bf16)
  const int tid  = threadIdx.x;
  const int wid  = tid >> 6;
  const int lane = tid & 63;
  const int g    = lane >> 4;    // k-group
  const int cl   = lane & 15;    // A-row / B-col / C-col within tile
  const int tile_m = blockIdx.x & 127;
  const int s      = blockIdx.x >> 7;
  const long k0 = (long)s * KSLICE;

  const char* bsrc = (const char*)Bswz + k0 * 256 + (long)tid * 16;
  const float* aptr = A + (long)(tile_m * 128 + wid * 16 + cl) * MN + k0 + 8 * g;

  f32x4 acc[8] = {};

  // prologue: stage steps 0..2, one-time full drain + barrier
#pragma unroll
  for (int p = 0; p < 3; ++p) {
    u16* d = &Bs[p][0] + wid * 512;
    const char* src = bsrc + (long)p * 16384;
    async16(d, src);
    async16(d + 4096, src + 8192);
  }
  __syncthreads();

  for (int t = 0; t < NSTEPS; ++t) {
    // A loads first (so in-flight stages are strictly younger than A)
    const float* ap = aptr + (long)t * BK;
    f32x4 a0 = __builtin_nontemporal_load((const f32x4*)ap);
    f32x4 a1 = __builtin_nontemporal_load((const f32x4*)(ap + 4));
    f32x4 a2 = __builtin_nontemporal_load((const f32x4*)(ap + 32));
    f32x4 a3 = __builtin_nontemporal_load((const f32x4*)(ap + 36));
    if (t + 3 < NSTEPS) {  // stage 3 ahead; stays in flight across barriers
      u16* d = &Bs[(t + 3) & 3][0] + wid * 512;
      const char* src = bsrc + (long)(t + 3) * 16384;
      async16(d, src);
      async16(d + 4096, src + 8192);
    }
    s16x8 af0, af1;
#pragma unroll
    for (int j = 0; j < 4; ++j) {    // compiler's A-wait lands here (vmcnt<=2)
      af0[j]     = (short)f2bf(a0[j]);
      af0[4 + j] = (short)f2bf(a1[j]);
      af1[j]     = (short)f2bf(a2[j]);
      af1[4 + j] = (short)f2bf(a3[j]);
    }
    const u16x8* bb = (const u16x8*)&Bs[t & 3][0];
#pragma unroll
    for (int c = 0; c < 8; ++c) {
      u16x8 b0 = bb[g * 128 + 16 * c + cl];
      u16x8 b1 = bb[512 + g * 128 + 16 * c + cl];
      acc[c] = __builtin_amdgcn_mfma_f32_16x16x32_bf16(
          af0, __builtin_bit_cast(s16x8, b0), acc[c], 0, 0, 0);
      acc[c] = __builtin_amdgcn_mfma_f32_16x16x32_bf16(
          af1, __builtin_bit_cast(s16x8, b1), acc[c], 0, 0, 0);
    }
    __builtin_amdgcn_s_barrier();   // raw barrier: no vmcnt drain
  }

  // C/D layout (HW-verified): col = lane&15, row = 4*(lane>>4) + reg
  float* pb = P + ((long)s * MN + tile_m * 128 + wid * 16) * 128;
#pragma unroll
  for (int c = 0; c < 8; ++c)
#pragma unroll
    for (int q = 0; q < 4; ++q)
      __builtin_nontemporal_store(acc[c][q], &pb[(g * 4 + q) * 128 + 16 * c + cl]);
}

// ---------------------------------------------------------------------------
// K3: LH = sum_s P[s] + b2 (tile in LDS); then
//     B2 = bf16frag(LH @ W4);  R = LH @ res_w^T + res_b + b4
// ---------------------------------------------------------------------------
__global__ __launch_bounds__(256)
void k3_mid(const float* __restrict__ P, const float* __restrict__ b2,
            const float* __restrict__ W4, const float* __restrict__ res_w,
            const float* __restrict__ b4, const float* __restrict__ res_b,
            u16* __restrict__ B2, float* __restrict__ Rr) {
  __shared__ __align__(16) float hs[64 * 128];
  const int t = threadIdx.x;
  const long rowbase = (long)blockIdx.x * 64;
  const long base = rowbase * 32;            // f32x4 units (128/4 per row)
  const f32x4* P0 = (const f32x4*)P + base;
  const f32x4* P1 = (const f32x4*)P + (long)MN * 32 + base;
  const f32x4* P2 = (const f32x4*)P + 2L * MN * 32 + base;
  const f32x4* P3 = (const f32x4*)P + 3L * MN * 32 + base;
  const f32x4* b2v = (const f32x4*)b2;
  f32x4* hl = (f32x4*)hs;
#pragma unroll
  for (int i = 0; i < 8; ++i) {
    int idx = t + 256 * i;
    f32x4 v = __builtin_nontemporal_load(P0 + idx);
    v += __builtin_nontemporal_load(P1 + idx);
    v += __builtin_nontemporal_load(P2 + idx);
    v += __builtin_nontemporal_load(P3 + idx);
    hl[idx] = v + b2v[idx & 31];
  }
  __syncthreads();
  const int r0 = (t >> 5) * 8;
  const int c0 = (t & 31) * 4;
  float acc2[8][4] = {};
  float accR[8][4] = {};
  for (int k = 0; k < 128; k += 4) {
    f32x4 w4v[4], rwv[4];
#pragma unroll
    for (int kk = 0; kk < 4; ++kk) w4v[kk] = *(const f32x4*)(W4 + (k + kk) * 128 + c0);
#pragma unroll
    for (int j = 0; j < 4; ++j) rwv[j] = *(const f32x4*)(res_w + (c0 + j) * 128 + k);
#pragma unroll
    for (int i = 0; i < 8; ++i) {
      f32x4 xv = *(const f32x4*)(hs + (r0 + i) * 128 + k);
#pragma unroll
      for (int kk = 0; kk < 4; ++kk)
#pragma unroll
        for (int j = 0; j < 4; ++j) {
          acc2[i][j] += xv[kk] * w4v[kk][j];
          accR[i][j] += xv[kk] * rwv[j][kk];
        }
    }
  }
  const long R8 = (rowbase + r0) >> 3;
#pragma unroll
  for (int j = 0; j < 4; ++j) {
    u16x8 v;
#pragma unroll
    for (int i = 0; i < 8; ++i) v[i] = f2bf(acc2[i][j]);
    *(u16x8*)(B2 + (R8 * 128 + (c0 + j)) * 8) = v;
  }
  const f32x4 b4v = *(const f32x4*)(b4 + c0);
  const f32x4 rbv = *(const f32x4*)(res_b + c0);
#pragma unroll
  for (int i = 0; i < 8; ++i) {
    f32x4 rv;
#pragma unroll
    for (int j = 0; j < 4; ++j) rv[j] = accR[i][j];
    rv += b4v + rbv;
    *(f32x4*)(Rr + (rowbase + r0 + i) * 128 + c0) = rv;
  }
}

// ---------------------------------------------------------------------------
// K5: out = sum_s P[s] + R
// ---------------------------------------------------------------------------
__global__ __launch_bounds__(256)
void k5_out(const float* __restrict__ P, const float* __restrict__ Rr,
            float* __restrict__ out) {
  const long i = (long)blockIdx.x * 256 + threadIdx.x;   // f32x4 index
  const f32x4* P0 = (const f32x4*)P;
  const f32x4* P1 = P0 + (long)MN * 32;
  const f32x4* P2 = P0 + 2L * MN * 32;
  const f32x4* P3 = P0 + 3L * MN * 32;
  f32x4 v = __builtin_nontemporal_load(P0 + i);
  v += __builtin_nontemporal_load(P1 + i);
  v += __builtin_nontemporal_load(P2 + i);
  v += __builtin_nontemporal_load(P3 + i);
  v += *((const f32x4*)Rr + i);
  __builtin_nontemporal_store(v, (f32x4*)out + i);
}

extern "C" void kernel_launch(void* const* d_in, const int* in_sizes, int n_in,
                              void* d_out, int out_size, void* d_ws, size_t ws_size,
                              hipStream_t stream) {
  const float* x     = (const float*)d_in[0];
  const float* adj   = (const float*)d_in[1];
  const float* W2    = (const float*)d_in[2];
  const float* b2    = (const float*)d_in[3];
  const float* W4    = (const float*)d_in[4];
  const float* b4    = (const float*)d_in[5];
  const float* res_w = (const float*)d_in[6];
  const float* res_b = (const float*)d_in[7];
  float* out = (float*)d_out;

  char* ws = (char*)d_ws;
  u16*   B1 = (u16*)ws;                     // 4 MB  bf16-frag support1
  u16*   B2 = (u16*)(ws + (4L << 20));      // 4 MB  bf16-frag support2
  float* Rr = (float*)(ws + (8L << 20));    // 8 MB  residual + biases
  float* P  = (float*)(ws + (16L << 20));   // 32 MB split-K partials (reused)

  k1_xw2<<<dim3(256), dim3(256), 0, stream>>>(x, W2, B1);
  big_mm<<<dim3(128 * SPLITS), dim3(512), 0, stream>>>(adj, B1, P);
  k3_mid<<<dim3(256), dim3(256), 0, stream>>>(P, b2, W4, res_w, b4, res_b, B2, Rr);
  big_mm<<<dim3(128 * SPLITS), dim3(512), 0, stream>>>(adj, B2, P);
  k5_out<<<dim3(2048), dim3(256), 0, stream>>>(P, Rr, out);
}

// Round 4
// 473.902 us; speedup vs baseline: 1.6848x; 1.1854x over previous
//
#include <hip/hip_runtime.h>
#include <hip/hip_bf16.h>

#define MN 16384
#define SPLITS 4
#define KSLICE (MN / SPLITS)     // 4096
#define BK 64
#define NSTEPS (KSLICE / BK)     // 64

typedef float f32x4 __attribute__((ext_vector_type(4)));
typedef short s16x8 __attribute__((ext_vector_type(8)));
typedef unsigned short u16x8 __attribute__((ext_vector_type(8)));
typedef unsigned short u16;

__device__ __forceinline__ u16 f2bf(float f) {
  unsigned u = __builtin_bit_cast(unsigned, f);
  u += 0x7FFFu + ((u >> 16) & 1u);   // round-to-nearest-even
  return (u16)(u >> 16);
}

__device__ __forceinline__ void async16(void* lds, const void* g) {
  __builtin_amdgcn_global_load_lds(
      (const __attribute__((address_space(1))) unsigned int*)g,
      (__attribute__((address_space(3))) unsigned int*)lds, 16, 0, 0);
}

// ---------------------------------------------------------------------------
// K1: support1 = x @ W2, written as bf16 in MFMA-fragment order:
//     B1[( (k>>3)*128 + col )*8 + (k&7)]  (k = row index of support1)
// ---------------------------------------------------------------------------
__global__ __launch_bounds__(256)
void k1_xw2(const float* __restrict__ x, const float* __restrict__ W2,
            u16* __restrict__ B1) {
  __shared__ __align__(16) float xs[64 * 128];
  const int t = threadIdx.x;
  const long rowbase = (long)blockIdx.x * 64;
  const f32x4* xg = (const f32x4*)(x + rowbase * 128);
  f32x4* xl = (f32x4*)xs;
#pragma unroll
  for (int i = 0; i < 8; ++i) xl[t + 256 * i] = xg[t + 256 * i];
  __syncthreads();
  const int r0 = (t >> 5) * 8;   // 8 rows per thread (8-aligned)
  const int c0 = (t & 31) * 4;   // 4 cols per thread
  float acc[8][4] = {};
  for (int k = 0; k < 128; k += 4) {
    f32x4 w[4];
#pragma unroll
    for (int kk = 0; kk < 4; ++kk) w[kk] = *(const f32x4*)(W2 + (k + kk) * 128 + c0);
#pragma unroll
    for (int i = 0; i < 8; ++i) {
      f32x4 xv = *(const f32x4*)(xs + (r0 + i) * 128 + k);
#pragma unroll
      for (int kk = 0; kk < 4; ++kk)
#pragma unroll
        for (int j = 0; j < 4; ++j) acc[i][j] += xv[kk] * w[kk][j];
    }
  }
  const long R8 = (rowbase + r0) >> 3;
#pragma unroll
  for (int j = 0; j < 4; ++j) {
    u16x8 v;
#pragma unroll
    for (int i = 0; i < 8; ++i) v[i] = f2bf(acc[i][j]);
    *(u16x8*)(B1 + (R8 * 128 + (c0 + j)) * 8) = v;
  }
}

// ---------------------------------------------------------------------------
// Big kernel v4: P[s] = adj[:, k-slice s] @ B  (B in bf16 fragment order).
// K-relabel: lane(g,cl) owns k_phys = t*64 + g*16 + [0,16) -> its 16 A-floats
// per step are ONE contiguous 64B run (4 consecutive dwordx4, one addr calc,
// guaranteed L1 line reuse). A loads are PLAIN (no nontemporal -> L1 allocates).
// B fragments: MFMA m uses step-tile unit kk = 2g+m (GEMM is invariant under
// the global k-permutation; k1's packing unchanged).
// Sync: 3-buffer ring, stage(t+2), raw s_barrier, NO explicit waitcnt.
// Guarantee: compiler's wait for A(t) (vmcnt(2), stages younger) retires every
// wave's stage(t+1) during step t, before the end-of-t barrier -> buf (t+1) is
// fully written before any step-(t+1) ds_read. Overwrite of buf (t+2)%3 is
// safe: its previous readers' data-deps completed before barrier(end t-1).
// ---------------------------------------------------------------------------
__global__ __launch_bounds__(512, 4)
void big_mm(const float* __restrict__ A, const u16* __restrict__ Bswz,
            float* __restrict__ P) {
  __shared__ __align__(16) u16 Bs[3][8192];   // 3 x 16 KB (BK=64 x 128 bf16)
  const int tid  = threadIdx.x;
  const int wid  = tid >> 6;
  const int lane = tid & 63;
  const int g    = lane >> 4;    // k-group
  const int cl   = lane & 15;    // A-row / B-col / C-col within tile
  const int tile_m = blockIdx.x & 127;
  const int s      = blockIdx.x >> 7;
  const long k0 = (long)s * KSLICE;

  const char* bsrc = (const char*)Bswz + k0 * 256 + (long)tid * 16;
  const float* aptr = A + (long)(tile_m * 128 + wid * 16 + cl) * MN + k0 + 16 * g;

  f32x4 acc[8] = {};

  // prologue: stage steps 0..1, one-time full drain + barrier
#pragma unroll
  for (int p = 0; p < 2; ++p) {
    u16* d = &Bs[p][0] + wid * 512;
    const char* src = bsrc + (long)p * 16384;
    async16(d, src);
    async16(d + 4096, src + 8192);
  }
  __syncthreads();

  int cur = 0;             // buffer holding step t
  int nxt = 2;             // buffer to stage step t+2 into
  for (int t = 0; t < NSTEPS; ++t) {
    // A: one contiguous 64B run per lane (4 consecutive dwordx4)
    const float* ap = aptr + (long)t * BK;
    f32x4 a0 = *(const f32x4*)ap;
    f32x4 a1 = *(const f32x4*)(ap + 4);
    f32x4 a2 = *(const f32x4*)(ap + 8);
    f32x4 a3 = *(const f32x4*)(ap + 12);
    if (t + 2 < NSTEPS) {  // stage 2 ahead; stays in flight across barriers
      u16* d = &Bs[0][0] + nxt * 8192 + wid * 512;
      const char* src = bsrc + (long)(t + 2) * 16384;
      async16(d, src);
      async16(d + 4096, src + 8192);
    }
    s16x8 af0, af1;
#pragma unroll
    for (int j = 0; j < 4; ++j) {    // compiler's A-wait lands here (vmcnt<=2)
      af0[j]     = (short)f2bf(a0[j]);
      af0[4 + j] = (short)f2bf(a1[j]);
      af1[j]     = (short)f2bf(a2[j]);
      af1[4 + j] = (short)f2bf(a3[j]);
    }
    const u16x8* bb = (const u16x8*)(&Bs[0][0] + cur * 8192);
#pragma unroll
    for (int c = 0; c < 8; ++c) {
      u16x8 b0 = bb[(2 * g) * 128 + 16 * c + cl];       // k = 64t+16g+[0,8)
      u16x8 b1 = bb[(2 * g + 1) * 128 + 16 * c + cl];   // k = 64t+16g+[8,16)
      acc[c] = __builtin_amdgcn_mfma_f32_16x16x32_bf16(
          af0, __builtin_bit_cast(s16x8, b0), acc[c], 0, 0, 0);
      acc[c] = __builtin_amdgcn_mfma_f32_16x16x32_bf16(
          af1, __builtin_bit_cast(s16x8, b1), acc[c], 0, 0, 0);
    }
    __builtin_amdgcn_s_barrier();   // raw barrier: no vmcnt drain
    cur = (cur == 2) ? 0 : cur + 1;
    nxt = (nxt == 2) ? 0 : nxt + 1;
  }

  // C/D layout (HW-verified): col = lane&15, row = 4*(lane>>4) + reg
  float* pb = P + ((long)s * MN + tile_m * 128 + wid * 16) * 128;
#pragma unroll
  for (int c = 0; c < 8; ++c)
#pragma unroll
    for (int q = 0; q < 4; ++q)
      __builtin_nontemporal_store(acc[c][q], &pb[(g * 4 + q) * 128 + 16 * c + cl]);
}

// ---------------------------------------------------------------------------
// K3: LH = sum_s P[s] + b2 (tile in LDS); then
//     B2 = bf16frag(LH @ W4);  R = LH @ res_w^T + res_b + b4
// ---------------------------------------------------------------------------
__global__ __launch_bounds__(256)
void k3_mid(const float* __restrict__ P, const float* __restrict__ b2,
            const float* __restrict__ W4, const float* __restrict__ res_w,
            const float* __restrict__ b4, const float* __restrict__ res_b,
            u16* __restrict__ B2, float* __restrict__ Rr) {
  __shared__ __align__(16) float hs[64 * 128];
  const int t = threadIdx.x;
  const long rowbase = (long)blockIdx.x * 64;
  const long base = rowbase * 32;            // f32x4 units (128/4 per row)
  const f32x4* P0 = (const f32x4*)P + base;
  const f32x4* P1 = (const f32x4*)P + (long)MN * 32 + base;
  const f32x4* P2 = (const f32x4*)P + 2L * MN * 32 + base;
  const f32x4* P3 = (const f32x4*)P + 3L * MN * 32 + base;
  const f32x4* b2v = (const f32x4*)b2;
  f32x4* hl = (f32x4*)hs;
#pragma unroll
  for (int i = 0; i < 8; ++i) {
    int idx = t + 256 * i;
    f32x4 v = __builtin_nontemporal_load(P0 + idx);
    v += __builtin_nontemporal_load(P1 + idx);
    v += __builtin_nontemporal_load(P2 + idx);
    v += __builtin_nontemporal_load(P3 + idx);
    hl[idx] = v + b2v[idx & 31];
  }
  __syncthreads();
  const int r0 = (t >> 5) * 8;
  const int c0 = (t & 31) * 4;
  float acc2[8][4] = {};
  float accR[8][4] = {};
  for (int k = 0; k < 128; k += 4) {
    f32x4 w4v[4], rwv[4];
#pragma unroll
    for (int kk = 0; kk < 4; ++kk) w4v[kk] = *(const f32x4*)(W4 + (k + kk) * 128 + c0);
#pragma unroll
    for (int j = 0; j < 4; ++j) rwv[j] = *(const f32x4*)(res_w + (c0 + j) * 128 + k);
#pragma unroll
    for (int i = 0; i < 8; ++i) {
      f32x4 xv = *(const f32x4*)(hs + (r0 + i) * 128 + k);
#pragma unroll
      for (int kk = 0; kk < 4; ++kk)
#pragma unroll
        for (int j = 0; j < 4; ++j) {
          acc2[i][j] += xv[kk] * w4v[kk][j];
          accR[i][j] += xv[kk] * rwv[j][kk];
        }
    }
  }
  const long R8 = (rowbase + r0) >> 3;
#pragma unroll
  for (int j = 0; j < 4; ++j) {
    u16x8 v;
#pragma unroll
    for (int i = 0; i < 8; ++i) v[i] = f2bf(acc2[i][j]);
    *(u16x8*)(B2 + (R8 * 128 + (c0 + j)) * 8) = v;
  }
  const f32x4 b4v = *(const f32x4*)(b4 + c0);
  const f32x4 rbv = *(const f32x4*)(res_b + c0);
#pragma unroll
  for (int i = 0; i < 8; ++i) {
    f32x4 rv;
#pragma unroll
    for (int j = 0; j < 4; ++j) rv[j] = accR[i][j];
    rv += b4v + rbv;
    *(f32x4*)(Rr + (rowbase + r0 + i) * 128 + c0) = rv;
  }
}

// ---------------------------------------------------------------------------
// K5: out = sum_s P[s] + R
// ---------------------------------------------------------------------------
__global__ __launch_bounds__(256)
void k5_out(const float* __restrict__ P, const float* __restrict__ Rr,
            float* __restrict__ out) {
  const long i = (long)blockIdx.x * 256 + threadIdx.x;   // f32x4 index
  const f32x4* P0 = (const f32x4*)P;
  const f32x4* P1 = P0 + (long)MN * 32;
  const f32x4* P2 = P0 + 2L * MN * 32;
  const f32x4* P3 = P0 + 3L * MN * 32;
  f32x4 v = __builtin_nontemporal_load(P0 + i);
  v += __builtin_nontemporal_load(P1 + i);
  v += __builtin_nontemporal_load(P2 + i);
  v += __builtin_nontemporal_load(P3 + i);
  v += *((const f32x4*)Rr + i);
  __builtin_nontemporal_store(v, (f32x4*)out + i);
}

extern "C" void kernel_launch(void* const* d_in, const int* in_sizes, int n_in,
                              void* d_out, int out_size, void* d_ws, size_t ws_size,
                              hipStream_t stream) {
  const float* x     = (const float*)d_in[0];
  const float* adj   = (const float*)d_in[1];
  const float* W2    = (const float*)d_in[2];
  const float* b2    = (const float*)d_in[3];
  const float* W4    = (const float*)d_in[4];
  const float* b4    = (const float*)d_in[5];
  const float* res_w = (const float*)d_in[6];
  const float* res_b = (const float*)d_in[7];
  float* out = (float*)d_out;

  char* ws = (char*)d_ws;
  u16*   B1 = (u16*)ws;                     // 4 MB  bf16-frag support1
  u16*   B2 = (u16*)(ws + (4L << 20));      // 4 MB  bf16-frag support2
  float* Rr = (float*)(ws + (8L << 20));    // 8 MB  residual + biases
  float* P  = (float*)(ws + (16L << 20));   // 32 MB split-K partials (reused)

  k1_xw2<<<dim3(256), dim3(256), 0, stream>>>(x, W2, B1);
  big_mm<<<dim3(128 * SPLITS), dim3(512), 0, stream>>>(adj, B1, P);
  k3_mid<<<dim3(256), dim3(256), 0, stream>>>(P, b2, W4, res_w, b4, res_b, B2, Rr);
  big_mm<<<dim3(128 * SPLITS), dim3(512), 0, stream>>>(adj, B2, P);
  k5_out<<<dim3(2048), dim3(256), 0, stream>>>(P, Rr, out);
}

// Round 5
// 449.712 us; speedup vs baseline: 1.7754x; 1.0538x over previous
//
#include <hip/hip_runtime.h>
#include <hip/hip_bf16.h>

#define MN 16384
#define SPLITS 4
#define KSLICE (MN / SPLITS)     // 4096
#define BK 64
#define NSTEPS (KSLICE / BK)     // 64

typedef float f32x4 __attribute__((ext_vector_type(4)));
typedef float f32x2 __attribute__((ext_vector_type(2)));
typedef int   i32x4 __attribute__((ext_vector_type(4)));
typedef short s16x8 __attribute__((ext_vector_type(8)));
typedef unsigned short u16x8 __attribute__((ext_vector_type(8)));
typedef unsigned short u16;

#define A8_SCALE 32768.0f        // adj * 2^15 in [0,2) -> fp8 e4m3 normal range

__device__ __forceinline__ u16 f2bf(float f) {
  unsigned u = __builtin_bit_cast(unsigned, f);
  u += 0x7FFFu + ((u >> 16) & 1u);   // round-to-nearest-even
  return (u16)(u >> 16);
}

__device__ __forceinline__ void async16(void* lds, const void* g) {
  __builtin_amdgcn_global_load_lds(
      (const __attribute__((address_space(1))) unsigned int*)g,
      (__attribute__((address_space(3))) unsigned int*)lds, 16, 0, 0);
}

// ---------------------------------------------------------------------------
// K1: support1 = x @ W2, written as bf16 in MFMA-fragment order:
//     B1[( (k>>3)*128 + col )*8 + (k&7)]  (k = row index of support1)
// ---------------------------------------------------------------------------
__global__ __launch_bounds__(256)
void k1_xw2(const float* __restrict__ x, const float* __restrict__ W2,
            u16* __restrict__ B1) {
  __shared__ __align__(16) float xs[64 * 128];
  const int t = threadIdx.x;
  const long rowbase = (long)blockIdx.x * 64;
  const f32x4* xg = (const f32x4*)(x + rowbase * 128);
  f32x4* xl = (f32x4*)xs;
#pragma unroll
  for (int i = 0; i < 8; ++i) xl[t + 256 * i] = xg[t + 256 * i];
  __syncthreads();
  const int r0 = (t >> 5) * 8;   // 8 rows per thread (8-aligned)
  const int c0 = (t & 31) * 4;   // 4 cols per thread
  float acc[8][4] = {};
  for (int k = 0; k < 128; k += 4) {
    f32x4 w[4];
#pragma unroll
    for (int kk = 0; kk < 4; ++kk) w[kk] = *(const f32x4*)(W2 + (k + kk) * 128 + c0);
#pragma unroll
    for (int i = 0; i < 8; ++i) {
      f32x4 xv = *(const f32x4*)(xs + (r0 + i) * 128 + k);
#pragma unroll
      for (int kk = 0; kk < 4; ++kk)
#pragma unroll
        for (int j = 0; j < 4; ++j) acc[i][j] += xv[kk] * w[kk][j];
    }
  }
  const long R8 = (rowbase + r0) >> 3;
#pragma unroll
  for (int j = 0; j < 4; ++j) {
    u16x8 v;
#pragma unroll
    for (int i = 0; i < 8; ++i) v[i] = f2bf(acc[i][j]);
    *(u16x8*)(B1 + (R8 * 128 + (c0 + j)) * 8) = v;
  }
}

// ---------------------------------------------------------------------------
// Big kernel v5: P[s] = adj[:, k-slice s] @ B  (B in bf16 fragment order).
// AMODE 0: A = f32 adj (R4 path: contiguous 64B run per lane) + side-product
//          fp8(adj * 2^15) copy written in pass-2 consumption order
//          (8 KB contiguous per (block,step), lane i at byte 16*i).
// AMODE 1: A = fp8 copy: ONE dwordx4 per lane per step, perfectly sequential;
//          reg-prefetch 1 step ahead; decode fp8->f32->bf16; epilogue *2^-15.
// AMODE 2: A = f32 adj, no copy (ws-too-small fallback; == R4).
// Sync: 3-buffer LDS ring for B, stage(t+2), raw s_barrier, no explicit
// waitcnt (compiler's A(t)-wait retires stage(t+1) before each barrier).
// ---------------------------------------------------------------------------
template <int AMODE>
__global__ __launch_bounds__(512, 4)
void big_mm(const float* __restrict__ A, const unsigned char* __restrict__ A8r,
            unsigned char* __restrict__ A8w, const u16* __restrict__ Bswz,
            float* __restrict__ P) {
  __shared__ __align__(16) u16 Bs[3][8192];   // 3 x 16 KB (BK=64 x 128 bf16)
  const int tid  = threadIdx.x;
  const int wid  = tid >> 6;
  const int lane = tid & 63;
  const int g    = lane >> 4;    // k-group
  const int cl   = lane & 15;    // A-row / B-col / C-col within tile
  const int tile_m = blockIdx.x & 127;
  const int s      = blockIdx.x >> 7;
  const long k0 = (long)s * KSLICE;

  const char* bsrc = (const char*)Bswz + k0 * 256 + (long)tid * 16;
  const float* aptr = A + (long)(tile_m * 128 + wid * 16 + cl) * MN + k0 + 16 * g;
  // fp8 copy: chunk per (s,tile_m,step) of 512*16B, lane-linear
  const long c8base = (((long)s * 128 + tile_m) * 64 * 512 + tid) * 16;

  f32x4 acc[8] = {};

  // prologue: stage steps 0..1, one-time full drain + barrier
#pragma unroll
  for (int p = 0; p < 2; ++p) {
    u16* d = &Bs[p][0] + wid * 512;
    const char* src = bsrc + (long)p * 16384;
    async16(d, src);
    async16(d + 4096, src + 8192);
  }
  __syncthreads();

  i32x4 a8nxt;
  if constexpr (AMODE == 1) a8nxt = *(const i32x4*)(A8r + c8base);

  int cur = 0;             // buffer holding step t
  int nxt = 2;             // buffer to stage step t+2 into
  for (int t = 0; t < NSTEPS; ++t) {
    s16x8 af0, af1;
    if constexpr (AMODE == 1) {
      i32x4 a8 = a8nxt;
      if (t + 1 < NSTEPS)
        a8nxt = *(const i32x4*)(A8r + c8base + (long)(t + 1) * 8192);
      if (t + 2 < NSTEPS) {
        u16* d = &Bs[0][0] + nxt * 8192 + wid * 512;
        const char* src = bsrc + (long)(t + 2) * 16384;
        async16(d, src);
        async16(d + 4096, src + 8192);
      }
      // decode 16 fp8 -> bf16 (dword d holds k-bytes 4d..4d+3)
#pragma unroll
      for (int d = 0; d < 2; ++d) {
        f32x2 lo = __builtin_amdgcn_cvt_pk_f32_fp8(a8[d], false);
        f32x2 hi = __builtin_amdgcn_cvt_pk_f32_fp8(a8[d], true);
        af0[4 * d + 0] = (short)f2bf(lo[0]);
        af0[4 * d + 1] = (short)f2bf(lo[1]);
        af0[4 * d + 2] = (short)f2bf(hi[0]);
        af0[4 * d + 3] = (short)f2bf(hi[1]);
      }
#pragma unroll
      for (int d = 0; d < 2; ++d) {
        f32x2 lo = __builtin_amdgcn_cvt_pk_f32_fp8(a8[d + 2], false);
        f32x2 hi = __builtin_amdgcn_cvt_pk_f32_fp8(a8[d + 2], true);
        af1[4 * d + 0] = (short)f2bf(lo[0]);
        af1[4 * d + 1] = (short)f2bf(lo[1]);
        af1[4 * d + 2] = (short)f2bf(hi[0]);
        af1[4 * d + 3] = (short)f2bf(hi[1]);
      }
    } else {
      // A: one contiguous 64B run per lane (4 consecutive dwordx4)
      const float* ap = aptr + (long)t * BK;
      f32x4 a0 = *(const f32x4*)ap;
      f32x4 a1 = *(const f32x4*)(ap + 4);
      f32x4 a2 = *(const f32x4*)(ap + 8);
      f32x4 a3 = *(const f32x4*)(ap + 12);
      if (t + 2 < NSTEPS) {  // stage 2 ahead; stays in flight across barriers
        u16* d = &Bs[0][0] + nxt * 8192 + wid * 512;
        const char* src = bsrc + (long)(t + 2) * 16384;
        async16(d, src);
        async16(d + 4096, src + 8192);
      }
#pragma unroll
      for (int j = 0; j < 4; ++j) {   // compiler's A-wait lands here
        af0[j]     = (short)f2bf(a0[j]);
        af0[4 + j] = (short)f2bf(a1[j]);
        af1[j]     = (short)f2bf(a2[j]);
        af1[4 + j] = (short)f2bf(a3[j]);
      }
      if constexpr (AMODE == 0) {     // fp8 side-copy in pass-2 order
        i32x4 pk;
        pk[0] = __builtin_amdgcn_cvt_pk_fp8_f32(a0[0] * A8_SCALE, a0[1] * A8_SCALE, 0, false);
        pk[0] = __builtin_amdgcn_cvt_pk_fp8_f32(a0[2] * A8_SCALE, a0[3] * A8_SCALE, pk[0], true);
        pk[1] = __builtin_amdgcn_cvt_pk_fp8_f32(a1[0] * A8_SCALE, a1[1] * A8_SCALE, 0, false);
        pk[1] = __builtin_amdgcn_cvt_pk_fp8_f32(a1[2] * A8_SCALE, a1[3] * A8_SCALE, pk[1], true);
        pk[2] = __builtin_amdgcn_cvt_pk_fp8_f32(a2[0] * A8_SCALE, a2[1] * A8_SCALE, 0, false);
        pk[2] = __builtin_amdgcn_cvt_pk_fp8_f32(a2[2] * A8_SCALE, a2[3] * A8_SCALE, pk[2], true);
        pk[3] = __builtin_amdgcn_cvt_pk_fp8_f32(a3[0] * A8_SCALE, a3[1] * A8_SCALE, 0, false);
        pk[3] = __builtin_amdgcn_cvt_pk_fp8_f32(a3[2] * A8_SCALE, a3[3] * A8_SCALE, pk[3], true);
        __builtin_nontemporal_store(pk, (i32x4*)(A8w + c8base + (long)t * 8192));
      }
    }
    const u16x8* bb = (const u16x8*)(&Bs[0][0] + cur * 8192);
#pragma unroll
    for (int c = 0; c < 8; ++c) {
      u16x8 b0 = bb[(2 * g) * 128 + 16 * c + cl];       // k = 64t+16g+[0,8)
      u16x8 b1 = bb[(2 * g + 1) * 128 + 16 * c + cl];   // k = 64t+16g+[8,16)
      acc[c] = __builtin_amdgcn_mfma_f32_16x16x32_bf16(
          af0, __builtin_bit_cast(s16x8, b0), acc[c], 0, 0, 0);
      acc[c] = __builtin_amdgcn_mfma_f32_16x16x32_bf16(
          af1, __builtin_bit_cast(s16x8, b1), acc[c], 0, 0, 0);
    }
    __builtin_amdgcn_s_barrier();   // raw barrier: no vmcnt drain
    cur = (cur == 2) ? 0 : cur + 1;
    nxt = (nxt == 2) ? 0 : nxt + 1;
  }

  // C/D layout (HW-verified): col = lane&15, row = 4*(lane>>4) + reg
  const float sc = (AMODE == 1) ? (1.0f / A8_SCALE) : 1.0f;
  float* pb = P + ((long)s * MN + tile_m * 128 + wid * 16) * 128;
#pragma unroll
  for (int c = 0; c < 8; ++c)
#pragma unroll
    for (int q = 0; q < 4; ++q)
      __builtin_nontemporal_store(acc[c][q] * sc,
                                  &pb[(g * 4 + q) * 128 + 16 * c + cl]);
}

// ---------------------------------------------------------------------------
// K3: LH = sum_s P[s] + b2 (tile in LDS); then
//     B2 = bf16frag(LH @ W4);  R = LH @ res_w^T + res_b + b4
// ---------------------------------------------------------------------------
__global__ __launch_bounds__(256)
void k3_mid(const float* __restrict__ P, const float* __restrict__ b2,
            const float* __restrict__ W4, const float* __restrict__ res_w,
            const float* __restrict__ b4, const float* __restrict__ res_b,
            u16* __restrict__ B2, float* __restrict__ Rr) {
  __shared__ __align__(16) float hs[64 * 128];
  const int t = threadIdx.x;
  const long rowbase = (long)blockIdx.x * 64;
  const long base = rowbase * 32;            // f32x4 units (128/4 per row)
  const f32x4* P0 = (const f32x4*)P + base;
  const f32x4* P1 = (const f32x4*)P + (long)MN * 32 + base;
  const f32x4* P2 = (const f32x4*)P + 2L * MN * 32 + base;
  const f32x4* P3 = (const f32x4*)P + 3L * MN * 32 + base;
  const f32x4* b2v = (const f32x4*)b2;
  f32x4* hl = (f32x4*)hs;
#pragma unroll
  for (int i = 0; i < 8; ++i) {
    int idx = t + 256 * i;
    f32x4 v = __builtin_nontemporal_load(P0 + idx);
    v += __builtin_nontemporal_load(P1 + idx);
    v += __builtin_nontemporal_load(P2 + idx);
    v += __builtin_nontemporal_load(P3 + idx);
    hl[idx] = v + b2v[idx & 31];
  }
  __syncthreads();
  const int r0 = (t >> 5) * 8;
  const int c0 = (t & 31) * 4;
  float acc2[8][4] = {};
  float accR[8][4] = {};
  for (int k = 0; k < 128; k += 4) {
    f32x4 w4v[4], rwv[4];
#pragma unroll
    for (int kk = 0; kk < 4; ++kk) w4v[kk] = *(const f32x4*)(W4 + (k + kk) * 128 + c0);
#pragma unroll
    for (int j = 0; j < 4; ++j) rwv[j] = *(const f32x4*)(res_w + (c0 + j) * 128 + k);
#pragma unroll
    for (int i = 0; i < 8; ++i) {
      f32x4 xv = *(const f32x4*)(hs + (r0 + i) * 128 + k);
#pragma unroll
      for (int kk = 0; kk < 4; ++kk)
#pragma unroll
        for (int j = 0; j < 4; ++j) {
          acc2[i][j] += xv[kk] * w4v[kk][j];
          accR[i][j] += xv[kk] * rwv[j][kk];
        }
    }
  }
  const long R8 = (rowbase + r0) >> 3;
#pragma unroll
  for (int j = 0; j < 4; ++j) {
    u16x8 v;
#pragma unroll
    for (int i = 0; i < 8; ++i) v[i] = f2bf(acc2[i][j]);
    *(u16x8*)(B2 + (R8 * 128 + (c0 + j)) * 8) = v;
  }
  const f32x4 b4v = *(const f32x4*)(b4 + c0);
  const f32x4 rbv = *(const f32x4*)(res_b + c0);
#pragma unroll
  for (int i = 0; i < 8; ++i) {
    f32x4 rv;
#pragma unroll
    for (int j = 0; j < 4; ++j) rv[j] = accR[i][j];
    rv += b4v + rbv;
    *(f32x4*)(Rr + (rowbase + r0 + i) * 128 + c0) = rv;
  }
}

// ---------------------------------------------------------------------------
// K5: out = sum_s P[s] + R
// ---------------------------------------------------------------------------
__global__ __launch_bounds__(256)
void k5_out(const float* __restrict__ P, const float* __restrict__ Rr,
            float* __restrict__ out) {
  const long i = (long)blockIdx.x * 256 + threadIdx.x;   // f32x4 index
  const f32x4* P0 = (const f32x4*)P;
  const f32x4* P1 = P0 + (long)MN * 32;
  const f32x4* P2 = P0 + 2L * MN * 32;
  const f32x4* P3 = P0 + 3L * MN * 32;
  f32x4 v = __builtin_nontemporal_load(P0 + i);
  v += __builtin_nontemporal_load(P1 + i);
  v += __builtin_nontemporal_load(P2 + i);
  v += __builtin_nontemporal_load(P3 + i);
  v += *((const f32x4*)Rr + i);
  __builtin_nontemporal_store(v, (f32x4*)out + i);
}

extern "C" void kernel_launch(void* const* d_in, const int* in_sizes, int n_in,
                              void* d_out, int out_size, void* d_ws, size_t ws_size,
                              hipStream_t stream) {
  const float* x     = (const float*)d_in[0];
  const float* adj   = (const float*)d_in[1];
  const float* W2    = (const float*)d_in[2];
  const float* b2    = (const float*)d_in[3];
  const float* W4    = (const float*)d_in[4];
  const float* b4    = (const float*)d_in[5];
  const float* res_w = (const float*)d_in[6];
  const float* res_b = (const float*)d_in[7];
  float* out = (float*)d_out;

  char* ws = (char*)d_ws;
  u16*   B1 = (u16*)ws;                     // 4 MB  bf16-frag support1
  u16*   B2 = (u16*)(ws + (4L << 20));      // 4 MB  bf16-frag support2
  float* Rr = (float*)(ws + (8L << 20));    // 8 MB  residual + biases
  float* P  = (float*)(ws + (16L << 20));   // 32 MB split-K partials (reused)
  unsigned char* A8 = (unsigned char*)(ws + (48L << 20));  // 256 MB fp8 adj

  const size_t need = (48L << 20) + (size_t)MN * MN;  // 318.8 MB
  const bool fp8_path = ws_size >= need;

  k1_xw2<<<dim3(256), dim3(256), 0, stream>>>(x, W2, B1);
  if (fp8_path) {
    big_mm<0><<<dim3(128 * SPLITS), dim3(512), 0, stream>>>(adj, nullptr, A8, B1, P);
    k3_mid<<<dim3(256), dim3(256), 0, stream>>>(P, b2, W4, res_w, b4, res_b, B2, Rr);
    big_mm<1><<<dim3(128 * SPLITS), dim3(512), 0, stream>>>(nullptr, A8, nullptr, B2, P);
  } else {
    big_mm<2><<<dim3(128 * SPLITS), dim3(512), 0, stream>>>(adj, nullptr, nullptr, B1, P);
    k3_mid<<<dim3(256), dim3(256), 0, stream>>>(P, b2, W4, res_w, b4, res_b, B2, Rr);
    big_mm<2><<<dim3(128 * SPLITS), dim3(512), 0, stream>>>(adj, nullptr, nullptr, B2, P);
  }
  k5_out<<<dim3(2048), dim3(256), 0, stream>>>(P, Rr, out);
}

// Round 6
// 443.451 us; speedup vs baseline: 1.8005x; 1.0141x over previous
//
#include <hip/hip_runtime.h>
#include <hip/hip_bf16.h>

#define MN 16384
#define SPLITS 4
#define KSLICE (MN / SPLITS)     // 4096
#define BK 64
#define NSTEPS (KSLICE / BK)     // 64

typedef float f32x4 __attribute__((ext_vector_type(4)));
typedef int   i32x4 __attribute__((ext_vector_type(4)));

#define A8S 32768.0f             // adj * 2^15 in [0,2)
#define SB1 64.0f                // support1 * 64  in ~[-170,170]
#define SB2 4096.0f              // support2 * 4096 in ~[-40,40]
#define SC1 (1.0f / (32768.0f * 64.0f))     // 2^-21
#define SC2 (1.0f / (32768.0f * 4096.0f))   // 2^-27

__device__ __forceinline__ void async16(void* lds, const void* g) {
  __builtin_amdgcn_global_load_lds(
      (const __attribute__((address_space(1))) unsigned int*)g,
      (__attribute__((address_space(3))) unsigned int*)lds, 16, 0, 0);
}

// fp8-fragment order for a [K x 128] operand: byte[(U*128 + col)*8 + j]
// holds fp8(val[k = U*8 + j][col]).  (unit U = k>>3, j = k&7)

// ---------------------------------------------------------------------------
// K1: support1 = x @ W2 -> fp8 e4m3 (x SB1) in fragment order.
// ---------------------------------------------------------------------------
__global__ __launch_bounds__(256)
void k1_xw2(const float* __restrict__ x, const float* __restrict__ W2,
            unsigned char* __restrict__ B1) {
  __shared__ __align__(16) float xs[64 * 128];
  const int t = threadIdx.x;
  const long rowbase = (long)blockIdx.x * 64;
  const f32x4* xg = (const f32x4*)(x + rowbase * 128);
  f32x4* xl = (f32x4*)xs;
#pragma unroll
  for (int i = 0; i < 8; ++i) xl[t + 256 * i] = xg[t + 256 * i];
  __syncthreads();
  const int r0 = (t >> 5) * 8;   // 8 rows per thread (8-aligned)
  const int c0 = (t & 31) * 4;   // 4 cols per thread
  float acc[8][4] = {};
  for (int k = 0; k < 128; k += 4) {
    f32x4 w[4];
#pragma unroll
    for (int kk = 0; kk < 4; ++kk) w[kk] = *(const f32x4*)(W2 + (k + kk) * 128 + c0);
#pragma unroll
    for (int i = 0; i < 8; ++i) {
      f32x4 xv = *(const f32x4*)(xs + (r0 + i) * 128 + k);
#pragma unroll
      for (int kk = 0; kk < 4; ++kk)
#pragma unroll
        for (int j = 0; j < 4; ++j) acc[i][j] += xv[kk] * w[kk][j];
    }
  }
  const long U = (rowbase + r0) >> 3;
  i32x4 wv0, wv1;
#pragma unroll
  for (int j = 0; j < 4; ++j) {
    int lo = __builtin_amdgcn_cvt_pk_fp8_f32(acc[0][j] * SB1, acc[1][j] * SB1, 0, false);
    lo     = __builtin_amdgcn_cvt_pk_fp8_f32(acc[2][j] * SB1, acc[3][j] * SB1, lo, true);
    int hi = __builtin_amdgcn_cvt_pk_fp8_f32(acc[4][j] * SB1, acc[5][j] * SB1, 0, false);
    hi     = __builtin_amdgcn_cvt_pk_fp8_f32(acc[6][j] * SB1, acc[7][j] * SB1, hi, true);
    if (j < 2) { wv0[2 * j] = lo; wv0[2 * j + 1] = hi; }
    else       { wv1[2 * (j - 2)] = lo; wv1[2 * (j - 2) + 1] = hi; }
  }
  *(i32x4*)(B1 + (U * 128 + c0) * 8)      = wv0;
  *(i32x4*)(B1 + (U * 128 + c0) * 8 + 16) = wv1;
}

// ---------------------------------------------------------------------------
// Big kernel v6: P[s] = adj[:, k-slice s] @ B, fp8 e4m3 MFMA end-to-end.
// 256 threads / 4 waves; 64-row tile; grid = SPLITS*256.
// AMODE 0: A read f32 (contiguous 64B run/lane, prefetch 1 step), cvt->fp8
//          once; bytes feed BOTH the MFMA A-operand and the A8 side-copy.
// AMODE 1: A read from fp8 copy (1 dwordx4/lane/step, prefetch 1 step),
//          bytes feed MFMA directly (zero decode VALU).
// AMODE 2: like 0 but no A8 store (ws-too-small fallback).
// Sync: 3-buffer LDS ring for B (8 KB/step), stage(t+2) issued FIRST
// (sched_barrier pins issue order), counted vmcnt before raw s_barrier:
// in-order vmcnt retirement => retiring down to {stage(t+2) + A(t+1) [+st]}
// forces stage(t+1) complete before any wave crosses barrier(t).
// ---------------------------------------------------------------------------
template <int AMODE>
__global__ __launch_bounds__(256, 4)
void big_mm(const float* __restrict__ A, const unsigned char* __restrict__ A8r,
            unsigned char* __restrict__ A8w, const unsigned char* __restrict__ B8,
            float sc, float* __restrict__ P) {
  __shared__ __align__(16) unsigned char Bs[3 * 8192];
  const int tid  = threadIdx.x;
  const int wid  = tid >> 6;
  const int lane = tid & 63;
  const int g    = lane >> 4;    // k-group
  const int cl   = lane & 15;    // A-row / B-col / C-col within tile
  const int tile_m = blockIdx.x & 255;
  const int s      = blockIdx.x >> 8;
  const long k0 = (long)s * KSLICE;

  const char* bsrc = (const char*)B8 + k0 * 128 + (long)tid * 16;
  const float* aptr = nullptr;
  if constexpr (AMODE != 1)
    aptr = A + (long)(tile_m * 64 + wid * 16 + cl) * MN + k0 + 16 * g;
  const long c8base = (long)blockIdx.x * (64L * 4096) + (long)tid * 16;

  f32x4 acc[8] = {};

  // prologue: stage steps 0,1; prefetch A(0); one-time full drain
  {
    unsigned char* d0 = Bs + wid * 1024;
    async16(d0, bsrc);          async16(d0 + 4096, bsrc + 4096);
    unsigned char* d1 = Bs + 8192 + wid * 1024;
    async16(d1, bsrc + 8192);   async16(d1 + 4096, bsrc + 12288);
  }
  f32x4 a0n, a1n, a2n, a3n;
  i32x4 q8n;
  if constexpr (AMODE == 1) {
    q8n = *(const i32x4*)(A8r + c8base);
  } else {
    a0n = *(const f32x4*)aptr;       a1n = *(const f32x4*)(aptr + 4);
    a2n = *(const f32x4*)(aptr + 8); a3n = *(const f32x4*)(aptr + 12);
  }
  __syncthreads();

  int cur = 0, nxt = 2;
  for (int t = 0; t < NSTEPS; ++t) {
    // (1) stage B(t+2) FIRST — must be older than A(t+1) in VMEM issue order
    if (t + 2 < NSTEPS) {
      unsigned char* d = Bs + nxt * 8192 + wid * 1024;
      const char* src = bsrc + (long)(t + 2) * 8192;
      async16(d, src);  async16(d + 4096, src + 4096);
    }
    __builtin_amdgcn_sched_barrier(0);   // pin stage < A-load issue order

    // (2) rotate prefetched A(t) in, issue A(t+1)
    i32x4 pk;
    if constexpr (AMODE == 1) {
      pk = q8n;
      if (t + 1 < NSTEPS)
        q8n = *(const i32x4*)(A8r + c8base + (long)(t + 1) * 4096);
    } else {
      f32x4 a0 = a0n, a1 = a1n, a2 = a2n, a3 = a3n;
      if (t + 1 < NSTEPS) {
        const float* ap = aptr + (long)(t + 1) * BK;
        a0n = *(const f32x4*)ap;       a1n = *(const f32x4*)(ap + 4);
        a2n = *(const f32x4*)(ap + 8); a3n = *(const f32x4*)(ap + 12);
      }
      pk[0] = __builtin_amdgcn_cvt_pk_fp8_f32(a0[0] * A8S, a0[1] * A8S, 0, false);
      pk[0] = __builtin_amdgcn_cvt_pk_fp8_f32(a0[2] * A8S, a0[3] * A8S, pk[0], true);
      pk[1] = __builtin_amdgcn_cvt_pk_fp8_f32(a1[0] * A8S, a1[1] * A8S, 0, false);
      pk[1] = __builtin_amdgcn_cvt_pk_fp8_f32(a1[2] * A8S, a1[3] * A8S, pk[1], true);
      pk[2] = __builtin_amdgcn_cvt_pk_fp8_f32(a2[0] * A8S, a2[1] * A8S, 0, false);
      pk[2] = __builtin_amdgcn_cvt_pk_fp8_f32(a2[2] * A8S, a2[3] * A8S, pk[2], true);
      pk[3] = __builtin_amdgcn_cvt_pk_fp8_f32(a3[0] * A8S, a3[1] * A8S, 0, false);
      pk[3] = __builtin_amdgcn_cvt_pk_fp8_f32(a3[2] * A8S, a3[3] * A8S, pk[3], true);
      if constexpr (AMODE == 0)
        __builtin_nontemporal_store(pk, (i32x4*)(A8w + c8base + (long)t * 4096));
    }
    const long alo = ((long)(unsigned)pk[1] << 32) | (unsigned)pk[0];
    const long ahi = ((long)(unsigned)pk[3] << 32) | (unsigned)pk[2];

    // (3) MFMA: 8 col-tiles x 2 k-units (unit u = 2g+m at offset u*1024)
    const char* bb = (const char*)Bs + cur * 8192 + g * 2048 + cl * 8;
#pragma unroll
    for (int c = 0; c < 8; ++c) {
      long b0 = *(const long*)(bb + c * 128);
      long b1 = *(const long*)(bb + 1024 + c * 128);
      acc[c] = __builtin_amdgcn_mfma_f32_16x16x32_fp8_fp8(alo, b0, acc[c], 0, 0, 0);
      acc[c] = __builtin_amdgcn_mfma_f32_16x16x32_fp8_fp8(ahi, b1, acc[c], 0, 0, 0);
    }

    // (4) counted wait: retire stage(t+1) (oldest) w/o draining the pipeline
    if (t < NSTEPS - 2) {
      if constexpr (AMODE == 0)      asm volatile("s_waitcnt vmcnt(7)" ::: "memory");
      else if constexpr (AMODE == 2) asm volatile("s_waitcnt vmcnt(6)" ::: "memory");
      else                           asm volatile("s_waitcnt vmcnt(3)" ::: "memory");
    } else {
      asm volatile("s_waitcnt vmcnt(0)" ::: "memory");
    }
    __builtin_amdgcn_s_barrier();
    cur = (cur == 2) ? 0 : cur + 1;
    nxt = (nxt == 2) ? 0 : nxt + 1;
  }

  // C/D layout (HW-verified, dtype-independent): col=lane&15, row=4*(lane>>4)+q
  float* pb = P + ((long)s * MN + tile_m * 64 + wid * 16) * 128;
#pragma unroll
  for (int c = 0; c < 8; ++c)
#pragma unroll
    for (int q = 0; q < 4; ++q)
      __builtin_nontemporal_store(acc[c][q] * sc,
                                  &pb[(g * 4 + q) * 128 + 16 * c + cl]);
}

// ---------------------------------------------------------------------------
// K3: LH = sum_s P[s] + b2 (tile in LDS); then
//     B2 = fp8frag(LH @ W4 * SB2);  R = LH @ res_w^T + res_b + b4
// ---------------------------------------------------------------------------
__global__ __launch_bounds__(256)
void k3_mid(const float* __restrict__ P, const float* __restrict__ b2,
            const float* __restrict__ W4, const float* __restrict__ res_w,
            const float* __restrict__ b4, const float* __restrict__ res_b,
            unsigned char* __restrict__ B2, float* __restrict__ Rr) {
  __shared__ __align__(16) float hs[64 * 128];
  const int t = threadIdx.x;
  const long rowbase = (long)blockIdx.x * 64;
  const long base = rowbase * 32;            // f32x4 units (128/4 per row)
  const f32x4* P0 = (const f32x4*)P + base;
  const f32x4* P1 = (const f32x4*)P + (long)MN * 32 + base;
  const f32x4* P2 = (const f32x4*)P + 2L * MN * 32 + base;
  const f32x4* P3 = (const f32x4*)P + 3L * MN * 32 + base;
  const f32x4* b2v = (const f32x4*)b2;
  f32x4* hl = (f32x4*)hs;
#pragma unroll
  for (int i = 0; i < 8; ++i) {
    int idx = t + 256 * i;
    f32x4 v = __builtin_nontemporal_load(P0 + idx);
    v += __builtin_nontemporal_load(P1 + idx);
    v += __builtin_nontemporal_load(P2 + idx);
    v += __builtin_nontemporal_load(P3 + idx);
    hl[idx] = v + b2v[idx & 31];
  }
  __syncthreads();
  const int r0 = (t >> 5) * 8;
  const int c0 = (t & 31) * 4;
  float acc2[8][4] = {};
  float accR[8][4] = {};
  for (int k = 0; k < 128; k += 4) {
    f32x4 w4v[4], rwv[4];
#pragma unroll
    for (int kk = 0; kk < 4; ++kk) w4v[kk] = *(const f32x4*)(W4 + (k + kk) * 128 + c0);
#pragma unroll
    for (int j = 0; j < 4; ++j) rwv[j] = *(const f32x4*)(res_w + (c0 + j) * 128 + k);
#pragma unroll
    for (int i = 0; i < 8; ++i) {
      f32x4 xv = *(const f32x4*)(hs + (r0 + i) * 128 + k);
#pragma unroll
      for (int kk = 0; kk < 4; ++kk)
#pragma unroll
        for (int j = 0; j < 4; ++j) {
          acc2[i][j] += xv[kk] * w4v[kk][j];
          accR[i][j] += xv[kk] * rwv[j][kk];
        }
    }
  }
  const long U = (rowbase + r0) >> 3;
  i32x4 wv0, wv1;
#pragma unroll
  for (int j = 0; j < 4; ++j) {
    int lo = __builtin_amdgcn_cvt_pk_fp8_f32(acc2[0][j] * SB2, acc2[1][j] * SB2, 0, false);
    lo     = __builtin_amdgcn_cvt_pk_fp8_f32(acc2[2][j] * SB2, acc2[3][j] * SB2, lo, true);
    int hi = __builtin_amdgcn_cvt_pk_fp8_f32(acc2[4][j] * SB2, acc2[5][j] * SB2, 0, false);
    hi     = __builtin_amdgcn_cvt_pk_fp8_f32(acc2[6][j] * SB2, acc2[7][j] * SB2, hi, true);
    if (j < 2) { wv0[2 * j] = lo; wv0[2 * j + 1] = hi; }
    else       { wv1[2 * (j - 2)] = lo; wv1[2 * (j - 2) + 1] = hi; }
  }
  *(i32x4*)(B2 + (U * 128 + c0) * 8)      = wv0;
  *(i32x4*)(B2 + (U * 128 + c0) * 8 + 16) = wv1;

  const f32x4 b4v = *(const f32x4*)(b4 + c0);
  const f32x4 rbv = *(const f32x4*)(res_b + c0);
#pragma unroll
  for (int i = 0; i < 8; ++i) {
    f32x4 rv;
#pragma unroll
    for (int j = 0; j < 4; ++j) rv[j] = accR[i][j];
    rv += b4v + rbv;
    *(f32x4*)(Rr + (rowbase + r0 + i) * 128 + c0) = rv;
  }
}

// ---------------------------------------------------------------------------
// K5: out = sum_s P[s] + R
// ---------------------------------------------------------------------------
__global__ __launch_bounds__(256)
void k5_out(const float* __restrict__ P, const float* __restrict__ Rr,
            float* __restrict__ out) {
  const long i = (long)blockIdx.x * 256 + threadIdx.x;   // f32x4 index
  const f32x4* P0 = (const f32x4*)P;
  const f32x4* P1 = P0 + (long)MN * 32;
  const f32x4* P2 = P0 + 2L * MN * 32;
  const f32x4* P3 = P0 + 3L * MN * 32;
  f32x4 v = __builtin_nontemporal_load(P0 + i);
  v += __builtin_nontemporal_load(P1 + i);
  v += __builtin_nontemporal_load(P2 + i);
  v += __builtin_nontemporal_load(P3 + i);
  v += *((const f32x4*)Rr + i);
  __builtin_nontemporal_store(v, (f32x4*)out + i);
}

extern "C" void kernel_launch(void* const* d_in, const int* in_sizes, int n_in,
                              void* d_out, int out_size, void* d_ws, size_t ws_size,
                              hipStream_t stream) {
  const float* x     = (const float*)d_in[0];
  const float* adj   = (const float*)d_in[1];
  const float* W2    = (const float*)d_in[2];
  const float* b2    = (const float*)d_in[3];
  const float* W4    = (const float*)d_in[4];
  const float* b4    = (const float*)d_in[5];
  const float* res_w = (const float*)d_in[6];
  const float* res_b = (const float*)d_in[7];
  float* out = (float*)d_out;

  char* ws = (char*)d_ws;
  unsigned char* B1 = (unsigned char*)ws;            // 2 MB fp8-frag support1
  unsigned char* B2 = (unsigned char*)(ws + (4L << 20));   // 2 MB fp8-frag support2
  float* Rr = (float*)(ws + (8L << 20));             // 8 MB residual + biases
  float* P  = (float*)(ws + (16L << 20));            // 32 MB split-K partials
  unsigned char* A8 = (unsigned char*)(ws + (48L << 20));  // 256 MB fp8 adj

  const size_t need = (48L << 20) + (size_t)MN * MN;  // 318.8 MB
  const bool fp8_copy = ws_size >= need;

  k1_xw2<<<dim3(256), dim3(256), 0, stream>>>(x, W2, B1);
  if (fp8_copy) {
    big_mm<0><<<dim3(256 * SPLITS), dim3(256), 0, stream>>>(adj, nullptr, A8, B1, SC1, P);
    k3_mid<<<dim3(256), dim3(256), 0, stream>>>(P, b2, W4, res_w, b4, res_b, B2, Rr);
    big_mm<1><<<dim3(256 * SPLITS), dim3(256), 0, stream>>>(nullptr, A8, nullptr, B2, SC2, P);
  } else {
    big_mm<2><<<dim3(256 * SPLITS), dim3(256), 0, stream>>>(adj, nullptr, nullptr, B1, SC1, P);
    k3_mid<<<dim3(256), dim3(256), 0, stream>>>(P, b2, W4, res_w, b4, res_b, B2, Rr);
    big_mm<2><<<dim3(256 * SPLITS), dim3(256), 0, stream>>>(adj, nullptr, nullptr, B2, SC2, P);
  }
  k5_out<<<dim3(2048), dim3(256), 0, stream>>>(P, Rr, out);
}